// Round 6
// baseline (398.755 us; speedup 1.0000x reference)
//
#include <hip/hip_runtime.h>
#include <math.h>

#define DMODEL 1024
#define NHEADS 16
#define DKH    64
#define SEQ    1024
#define BATCH  4
#define NREL   33

typedef unsigned short u16;
typedef unsigned int   u32;
typedef short s16x8 __attribute__((ext_vector_type(8)));
typedef u16   u16x8 __attribute__((ext_vector_type(8)));
typedef float f32x4 __attribute__((ext_vector_type(4)));

#define MFMA16(a, b, c) __builtin_amdgcn_mfma_f32_16x16x32_bf16((a), (b), (c), 0, 0, 0)

// fp32 -> bf16 bits, round-nearest-even
static __device__ __forceinline__ u16 f2b(float x) {
  unsigned u = __float_as_uint(x);
  u += 0x7fffu + ((u >> 16) & 1u);
  return (u16)(u >> 16);
}
static __device__ __forceinline__ float b2f(u16 b) {
  return __uint_as_float(((unsigned)b) << 16);
}

// async global->LDS, 16 B/lane (dest = wave-uniform base + lane*16)
static __device__ __forceinline__ void gload16(const void* g, void* l) {
  __builtin_amdgcn_global_load_lds(
      (const __attribute__((address_space(1))) u32*)g,
      (__attribute__((address_space(3))) u32*)l, 16, 0, 0);
}

// ---------------------------------------------------------------------------
// fp32 -> bf16, 3 tensors in one launch (z = which).  8 elems/thread.
// ---------------------------------------------------------------------------
__global__ __launch_bounds__(256) void conv3(
    const float* __restrict__ A0, const float* __restrict__ A1,
    const float* __restrict__ A2,
    u16* __restrict__ O0, u16* __restrict__ O1, u16* __restrict__ O2)
{
  const int z = blockIdx.y;
  const float* A = z == 0 ? A0 : (z == 1 ? A1 : A2);
  u16* O = z == 0 ? O0 : (z == 1 ? O1 : O2);
  const int i8 = (blockIdx.x * 256 + threadIdx.x) * 8;
  const float4 v0 = *(const float4*)&A[i8];
  const float4 v1 = *(const float4*)&A[i8 + 4];
  u16x8 o;
  o[0] = f2b(v0.x); o[1] = f2b(v0.y); o[2] = f2b(v0.z); o[3] = f2b(v0.w);
  o[4] = f2b(v1.x); o[5] = f2b(v1.y); o[6] = f2b(v1.z); o[7] = f2b(v1.w);
  *(u16x8*)&O[i8] = o;
}

// ---------------------------------------------------------------------------
// W fp32 [1024][1024] -> W2 [1024][2048] bf16 (hi | lo) — out-proj only.
// ---------------------------------------------------------------------------
__global__ __launch_bounds__(256) void conv_w_split(
    const float* __restrict__ W, u16* __restrict__ W2)
{
  const int i8 = (blockIdx.x * 256 + threadIdx.x) * 8;
  const int row = i8 >> 10, col = i8 & 1023;
  const float4 v0 = *(const float4*)&W[i8];
  const float4 v1 = *(const float4*)&W[i8 + 4];
  u16x8 h, l;
  h[0] = f2b(v0.x); l[0] = f2b(v0.x - b2f(h[0]));
  h[1] = f2b(v0.y); l[1] = f2b(v0.y - b2f(h[1]));
  h[2] = f2b(v0.z); l[2] = f2b(v0.z - b2f(h[2]));
  h[3] = f2b(v0.w); l[3] = f2b(v0.w - b2f(h[3]));
  h[4] = f2b(v1.x); l[4] = f2b(v1.x - b2f(h[4]));
  h[5] = f2b(v1.y); l[5] = f2b(v1.y - b2f(h[5]));
  h[6] = f2b(v1.z); l[6] = f2b(v1.z - b2f(h[6]));
  h[7] = f2b(v1.w); l[7] = f2b(v1.w - b2f(h[7]));
  u16* base = W2 + (size_t)row * 2048;
  *(u16x8*)&base[col]        = h;
  *(u16x8*)&base[1024 + col] = l;
}

// ---------------------------------------------------------------------------
// GEMM: C[m][n] = sum_k A[m][k]*W[n][k] + bias[n].  A bf16 [4096][1024].
// B2 [1024][BSTRIDE]; A col = (kt&31)*32 (re-read for hi|lo split when
// NKT=64).  128x128 tile, BK=32, 4 waves (2x2), per-wave 64x64 = 4x4 frags.
// Double-buffered global_load_lds, prefetch kt+1 while computing kt.
// omode 0: bf16 -> [B,H,S,64] (q/k)  1: bf16 -> [B,H,dk,S] (vT)  2: fp32
// ---------------------------------------------------------------------------
template<int NKT, int BSTRIDE>
__device__ __forceinline__ void gemm_body(
    const u16* __restrict__ A, const u16* __restrict__ B2,
    const float* __restrict__ bias, void* __restrict__ outp, const int omode)
{
  __shared__ __attribute__((aligned(16))) u16 As[2][128][32];
  __shared__ __attribute__((aligned(16))) u16 Bs[2][128][32];
  const int tid = threadIdx.x;
  const int m0 = blockIdx.x * 128, n0 = blockIdx.y * 128;
  const int w = tid >> 6, lane = tid & 63;
  const int wm = w >> 1, wn = w & 1;
  const int c = lane & 15, g = lane >> 4;

  const int sr = tid >> 2;            // staging row (i=0; i=1: +64)
  const int kc = (tid & 3) * 8;
  const u16* aP = A  + (size_t)(m0 + sr) * 1024 + kc;
  const u16* bP = B2 + (size_t)(n0 + sr) * BSTRIDE + kc;
  char* aD = (char*)As + w * 1024;
  char* bD = (char*)Bs + w * 1024;

  f32x4 acc[4][4];
  #pragma unroll
  for (int nf = 0; nf < 4; ++nf) {
    const float bv = bias[n0 + wn * 64 + nf * 16 + c];
    #pragma unroll
    for (int mf = 0; mf < 4; ++mf) acc[mf][nf] = (f32x4){bv, bv, bv, bv};
  }

  // prologue: stage kt=0 into buf 0
  gload16(aP,                       aD);
  gload16(aP + 64 * 1024,           aD + 4096);
  gload16(bP,                       bD);
  gload16(bP + (size_t)64 * BSTRIDE, bD + 4096);
  __syncthreads();

  for (int kt = 0; kt < NKT; ++kt) {
    const int cur = kt & 1;
    if (kt < NKT - 1) {
      const int kn = kt + 1;
      const u16* a  = aP + (kn & 31) * 32;
      const u16* bb = bP + kn * 32;
      char* ad = aD + (cur ^ 1) * 8192;
      char* bd = bD + (cur ^ 1) * 8192;
      gload16(a,                        ad);
      gload16(a + 64 * 1024,            ad + 4096);
      gload16(bb,                        bd);
      gload16(bb + (size_t)64 * BSTRIDE, bd + 4096);
    }
    const char* ab  = (const char*)As + cur * 8192;
    const char* bbk = (const char*)Bs + cur * 8192;
    s16x8 af[4], bf_[4];
    #pragma unroll
    for (int mf = 0; mf < 4; ++mf)
      af[mf] = *(const s16x8*)(ab + (wm * 64 + mf * 16 + c) * 64 + g * 16);
    #pragma unroll
    for (int nf = 0; nf < 4; ++nf)
      bf_[nf] = *(const s16x8*)(bbk + (wn * 64 + nf * 16 + c) * 64 + g * 16);
    #pragma unroll
    for (int mf = 0; mf < 4; ++mf)
      #pragma unroll
      for (int nf = 0; nf < 4; ++nf)
        acc[mf][nf] = MFMA16(af[mf], bf_[nf], acc[mf][nf]);
    __syncthreads();
  }

  // epilogue: m = m0+wm*64+mf*16+g*4+r ; n = n0+wn*64+nf*16+c
  #pragma unroll
  for (int mf = 0; mf < 4; ++mf) {
    #pragma unroll
    for (int nf = 0; nf < 4; ++nf) {
      const int mbase = m0 + wm * 64 + mf * 16 + g * 4;
      const int n = n0 + wn * 64 + nf * 16 + c;
      if (omode == 0) {
        u16* O = (u16*)outp;
        #pragma unroll
        for (int r = 0; r < 4; ++r) {
          const int m = mbase + r;
          const int b = m >> 10, sl = m & 1023, h = n >> 6, dk = n & 63;
          O[((size_t)(b * 16 + h) * 1024 + sl) * 64 + dk] = f2b(acc[mf][nf][r]);
        }
      } else if (omode == 1) {
        u16* O = (u16*)outp;
        ushort4 pk;
        pk.x = f2b(acc[mf][nf][0]);
        pk.y = f2b(acc[mf][nf][1]);
        pk.z = f2b(acc[mf][nf][2]);
        pk.w = f2b(acc[mf][nf][3]);
        const int b = mbase >> 10, sl = mbase & 1023, h = n >> 6, dk = n & 63;
        *(ushort4*)&O[((size_t)(b * 16 + h) * 64 + dk) * 1024 + sl] = pk;
      } else {
        float* O = (float*)outp;
        #pragma unroll
        for (int r = 0; r < 4; ++r)
          O[(size_t)(mbase + r) * 1024 + n] = acc[mf][nf][r];
      }
    }
  }
}

__global__ __launch_bounds__(256) void gemm_qkv(
    const u16* __restrict__ Xq, const u16* __restrict__ Xk, const u16* __restrict__ Xv,
    const u16* __restrict__ Wqb, const u16* __restrict__ Wkb, const u16* __restrict__ Wvb,
    const float* __restrict__ bq, const float* __restrict__ bk, const float* __restrict__ bv,
    u16* __restrict__ q2g, u16* __restrict__ k2g, u16* __restrict__ vTg)
{
  const int z = blockIdx.z;
  const u16* A    = z == 0 ? Xq  : (z == 1 ? Xk  : Xv);
  const u16* B2   = z == 0 ? Wqb : (z == 1 ? Wkb : Wvb);
  const float* bb = z == 0 ? bq  : (z == 1 ? bk  : bv);
  void* O         = z == 0 ? (void*)q2g : (z == 1 ? (void*)k2g : (void*)vTg);
  gemm_body<32, 1024>(A, B2, bb, O, z == 2 ? 1 : 0);
}

__global__ __launch_bounds__(256) void gemm_out2(
    const u16* __restrict__ A, const u16* __restrict__ B2,
    const float* __restrict__ bias, float* __restrict__ out)
{
  gemm_body<64, 2048>(A, B2, bias, out, 2);
}

// ---------------------------------------------------------------------------
// kmaxg[bh] = max over kv rows of ||k_row|| (bf16 values), * safety margin.
// ---------------------------------------------------------------------------
__global__ __launch_bounds__(256) void kmax_k(
    const u16* __restrict__ k2g, float* __restrict__ kmaxg)
{
  const int bh = blockIdx.x;
  const u16* base = k2g + (size_t)bh * (SEQ * DKH);
  const int tid = threadIdx.x;
  float mx = 0.f;
  #pragma unroll
  for (int rr = 0; rr < 4; ++rr) {
    const int row = rr * 256 + tid;
    float s = 0.f;
    #pragma unroll
    for (int j = 0; j < 8; ++j) {
      const u16x8 v = *(const u16x8*)&base[row * 64 + j * 8];
      #pragma unroll
      for (int q = 0; q < 8; ++q) { const float f = b2f(v[q]); s = fmaf(f, f, s); }
    }
    mx = fmaxf(mx, s);
  }
  #pragma unroll
  for (int off = 1; off < 64; off <<= 1) mx = fmaxf(mx, __shfl_xor(mx, off, 64));
  __shared__ float red[4];
  if ((tid & 63) == 0) red[tid >> 6] = mx;
  __syncthreads();
  if (tid == 0) {
    const float m = fmaxf(fmaxf(red[0], red[1]), fmaxf(red[2], red[3]));
    kmaxg[bh] = sqrtf(m) * 1.0005f;
  }
}

// ---------------------------------------------------------------------------
// MFMA flash attention, rel-pos bias, STATIC-BOUND softmax:
// bound_r = ||q_r||*kmax/8 + max_j bias[r][j]  >= true row max (Cauchy-
// Schwarz), so p = exp(s - bound) needs no online max/rescale and no
// per-tile cross-lane reductions (one shfl reduce at the very end).
// Off-diagonal kv tiles (13/16) have uniform clipped distance -> bias is a
// per-row register constant (zero LDS reads).  K/V staged via swizzled
// global_load_lds dbuf (round-5 scheme).  q_s/p_s share one LDS union ->
// 51 KB -> 3 blocks/CU.
// ---------------------------------------------------------------------------
__global__ __launch_bounds__(256) void attn4(
    const u16* __restrict__ q2g, const u16* __restrict__ k2g,
    const u16* __restrict__ vTg, const float* __restrict__ rel,
    const float* __restrict__ kmaxg, u16* __restrict__ ctx)
{
  __shared__ __attribute__((aligned(16))) u16 up_s[64][76];   // q (preamble) / p (loop)
  __shared__ __attribute__((aligned(16))) u16 k_s[2][4096];
  __shared__ __attribute__((aligned(16))) u16 v_s[2][4096];
  __shared__ float bias_s[64][33];
  __shared__ float bound_s[64];

  const int tid = threadIdx.x;
  const int w = tid >> 6, lane = tid & 63;
  const int c = lane & 15, g = lane >> 4;
  const int qt = blockIdx.x, hd = blockIdx.y, b = blockIdx.z;
  const int l0 = qt * 64, bh = b * 16 + hd;
  u16* qs = &up_s[0][0];                 // flat [64*64] during preamble

  const u16* kbase = k2g + (size_t)bh * (SEQ * DKH);   // [S][64]
  const u16* vbase = vTg + (size_t)bh * (DKH * SEQ);   // [64][S]

  // staging geometry (round-5 swizzle): chunk D = i*256+tid -> (r=D>>3, jj=D&7)
  // source chunk j = jj ^ (r&7); LDS dest linear.
  const int r0 = tid >> 3;
  const int j0 = (tid & 7) ^ (r0 & 7);
  const u16* kP = kbase + (size_t)r0 * 64 + j0 * 8;
  const u16* vP = vbase + (size_t)r0 * 1024 + j0 * 8;
  char* kD = (char*)k_s + w * 1024;
  char* vD = (char*)v_s + w * 1024;

  // ---- one-time q stage (64x64) + async stage of K/V tile 0 ----
  const u16* qsrc = q2g + ((size_t)bh * SEQ + l0) * 64;
  #pragma unroll
  for (int i = 0; i < 2; ++i) {
    const int f16 = tid * 2 + i;
    const int r = f16 >> 3, ch = (f16 & 7) * 8;
    *(uint4*)&qs[r * 64 + ch] = *(const uint4*)&qsrc[r * 64 + ch];
  }
  gload16(kP,         kD);
  gload16(kP + 2048,  kD + 4096);
  gload16(vP,         vD);
  gload16(vP + 32768, vD + 4096);
  __syncthreads();

  // ---- per-wave q fragments (read before p_s overwrites the union) ----
  s16x8 qf[2];
  #pragma unroll
  for (int ks = 0; ks < 2; ++ks)
    qf[ks] = *(const s16x8*)&qs[(w * 16 + c) * 64 + ks * 32 + g * 8];

  // ---- bias table: bias_s[r][j] = q_r . rel[j] (rotated cols: no conflicts)
  const int rot = (tid & 31) * 2;
  for (int e = tid; e < 64 * NREL; e += 256) {
    const int r = e / NREL;
    const int j = e - r * NREL;
    float s = 0.f;
    for (int d0 = 0; d0 < 64; ++d0) {
      const int d = (d0 + rot) & 63;
      s = fmaf(b2f(qs[r * 64 + d]), rel[j * 64 + d], s);
    }
    bias_s[r][j] = s;
  }
  __syncthreads();

  // ---- per-row static bound ----
  if (tid < 64) {
    float q2 = 0.f;
    for (int d0 = 0; d0 < 64; ++d0) {
      const int d = (d0 + rot) & 63;
      const float qv = b2f(qs[tid * 64 + d]);
      q2 = fmaf(qv, qv, q2);
    }
    float mb = bias_s[tid][0];
    #pragma unroll
    for (int j = 1; j < NREL; ++j) mb = fmaxf(mb, bias_s[tid][j]);
    bound_s[tid] = sqrtf(q2) * 1.0005f * kmaxg[bh] * 0.125f + mb;
  }
  __syncthreads();   // bound_s ready; q_s now dead -> union becomes p_s

  const int qb = w * 16 + g * 4;
  float bnd[4], cr0[4], cr32[4], part[4];
  #pragma unroll
  for (int r = 0; r < 4; ++r) {
    const int rr = qb + r;
    bnd[r]  = bound_s[rr];
    cr0[r]  = bias_s[rr][0]  - bnd[r];
    cr32[r] = bias_s[rr][32] - bnd[r];
    part[r] = 0.f;
  }
  f32x4 oacc[4];
  #pragma unroll
  for (int fd = 0; fd < 4; ++fd) oacc[fd] = (f32x4){0.f, 0.f, 0.f, 0.f};

  // swizzled read chunk offsets (bytes) for ks = 0,1
  const int cj = c & 7;
  const int jx0 = ((0 + g) ^ cj) * 16;
  const int jx1 = ((4 + g) ^ cj) * 16;

  for (int kt = 0; kt < SEQ / 64; ++kt) {
    const int cur = kt & 1;
    if (kt < SEQ / 64 - 1) {             // prefetch tile kt+1
      const size_t ko = (size_t)(kt + 1) * 4096;
      const size_t vo = (size_t)(kt + 1) * 64;
      char* kd = kD + (cur ^ 1) * 8192;
      char* vd = vD + (cur ^ 1) * 8192;
      gload16(kP + ko,         kd);
      gload16(kP + ko + 2048,  kd + 4096);
      gload16(vP + vo,         vd);
      gload16(vP + vo + 32768, vd + 4096);
    }

    // ---- QK^T from swizzled K tile ----
    const char* kb = (const char*)k_s + cur * 8192;
    f32x4 sc[4];
    #pragma unroll
    for (int f = 0; f < 4; ++f) {
      const int rb = (f * 16 + c) * 128;
      const s16x8 kf0 = *(const s16x8*)(kb + rb + jx0);
      const s16x8 kf1 = *(const s16x8*)(kb + rb + jx1);
      sc[f] = (f32x4){0.f, 0.f, 0.f, 0.f};
      sc[f] = MFMA16(qf[0], kf0, sc[f]);
      sc[f] = MFMA16(qf[1], kf1, sc[f]);
    }

    // ---- static-bound softmax (no reductions, no rescale) ----
    const bool diag = (kt + 1 >= qt) && (kt <= qt + 1);
    if (!diag) {
      #pragma unroll
      for (int r = 0; r < 4; ++r) {
        const float cr = (kt < qt) ? cr0[r] : cr32[r];
        #pragma unroll
        for (int f = 0; f < 4; ++f) {
          const float sv = __expf(fmaf(sc[f][r], 0.125f, cr));
          part[r] += sv;
          up_s[qb + r][f * 16 + c] = f2b(sv);
        }
      }
    } else {
      #pragma unroll
      for (int r = 0; r < 4; ++r) {
        const int rowg = l0 + qb + r;
        #pragma unroll
        for (int f = 0; f < 4; ++f) {
          const int colg = kt * 64 + f * 16 + c;
          int dd = colg - rowg;
          dd = (dd < -16 ? -16 : (dd > 16 ? 16 : dd)) + 16;
          const float sv = __expf(fmaf(sc[f][r], 0.125f, bias_s[qb + r][dd] - bnd[r]));
          part[r] += sv;
          up_s[qb + r][f * 16 + c] = f2b(sv);
        }
      }
    }

    // ---- P.V: wave-private p rows + swizzled V tile ----
    const char* vb = (const char*)v_s + cur * 8192;
    #pragma unroll
    for (int ks = 0; ks < 2; ++ks) {
      const s16x8 pa = *(const s16x8*)&up_s[w * 16 + c][ks * 32 + g * 8];
      const int jx = ks ? jx1 : jx0;
      #pragma unroll
      for (int fd = 0; fd < 4; ++fd) {
        const s16x8 vv = *(const s16x8*)(vb + (fd * 16 + c) * 128 + jx);
        oacc[fd] = MFMA16(pa, vv, oacc[fd]);
      }
    }
    __syncthreads();   // drains prefetch + protects k/v buffer reuse
  }

  // ---- one final reduction across the 16 c-lanes, normalize, write ----
  #pragma unroll
  for (int r = 0; r < 4; ++r) {
    #pragma unroll
    for (int off = 1; off < 16; off <<= 1) part[r] += __shfl_xor(part[r], off, 64);
  }
  #pragma unroll
  for (int r = 0; r < 4; ++r) {
    const float inv = 1.0f / part[r];
    const int row = l0 + qb + r;
    #pragma unroll
    for (int fd = 0; fd < 4; ++fd)
      ctx[((size_t)b * 1024 + row) * 1024 + hd * 64 + fd * 16 + c] = f2b(oacc[fd][r] * inv);
  }
}

// ---------------------------------------------------------------------------
extern "C" void kernel_launch(void* const* d_in, const int* in_sizes, int n_in,
                              void* d_out, int out_size, void* d_ws, size_t ws_size,
                              hipStream_t stream)
{
  (void)in_sizes; (void)n_in; (void)out_size; (void)ws_size;
  const float* Q   = (const float*)d_in[0];
  const float* K   = (const float*)d_in[1];
  const float* V   = (const float*)d_in[2];
  const float* Wq  = (const float*)d_in[3];
  const float* bq  = (const float*)d_in[4];
  const float* Wk  = (const float*)d_in[5];
  const float* bk  = (const float*)d_in[6];
  const float* Wv  = (const float*)d_in[7];
  const float* bv  = (const float*)d_in[8];
  const float* Wo  = (const float*)d_in[9];
  const float* bo  = (const float*)d_in[10];
  const float* rel = (const float*)d_in[11];
  float* out = (float*)d_out;

  // ws map (bytes), peak ~56.6 MB:
  //   Xq 0 | Xk 8.39M | Xv 16.78M | Wqb 25.17M (2M) | Wkb 27.26M | Wvb 29.36M
  //   | q2g 31.46M | k2g 39.85M | vTg 48.23M | kmaxg 56.62M
  // ctx reuses Xq, W2o (4M) reuses Xk — both dead after gemm_qkv.
  char* ws = (char*)d_ws;
  u16* Xq   = (u16*)(ws);
  u16* Xk   = (u16*)(ws + 8388608);
  u16* Xv   = (u16*)(ws + 16777216);
  u16* Wqb  = (u16*)(ws + 25165824);
  u16* Wkb  = (u16*)(ws + 27262976);
  u16* Wvb  = (u16*)(ws + 29360128);
  u16* q2g  = (u16*)(ws + 31457280);
  u16* k2g  = (u16*)(ws + 39845888);
  u16* vTg  = (u16*)(ws + 48234496);
  float* kmaxg = (float*)(ws + 56623104);
  u16* ctx  = Xq;
  u16* W2o  = Xk;

  const dim3 blk(256);
  conv3<<<dim3(2048, 3), blk, 0, stream>>>(Q, K, V, Xq, Xk, Xv);
  conv3<<<dim3(512, 3),  blk, 0, stream>>>(Wq, Wk, Wv, Wqb, Wkb, Wvb);

  gemm_qkv<<<dim3(32, 8, 3), blk, 0, stream>>>(Xq, Xk, Xv, Wqb, Wkb, Wvb,
                                               bq, bk, bv, q2g, k2g, vTg);

  kmax_k<<<dim3(NHEADS * BATCH), blk, 0, stream>>>(k2g, kmaxg);
  conv_w_split<<<dim3(512), blk, 0, stream>>>(Wo, W2o);

  attn4<<<dim3(SEQ / 64, NHEADS, BATCH), blk, 0, stream>>>(q2g, k2g, vTg, rel,
                                                           kmaxg, ctx);

  gemm_out2<<<dim3(32, 8), blk, 0, stream>>>(ctx, W2o, bo, out);
}

// Round 7
// 359.134 us; speedup vs baseline: 1.1103x; 1.1103x over previous
//
#include <hip/hip_runtime.h>
#include <math.h>

#define DMODEL 1024
#define NHEADS 16
#define DKH    64
#define SEQ    1024
#define BATCH  4
#define NREL   33

typedef unsigned short u16;
typedef unsigned int   u32;
typedef short s16x8 __attribute__((ext_vector_type(8)));
typedef u16   u16x8 __attribute__((ext_vector_type(8)));
typedef float f32x4 __attribute__((ext_vector_type(4)));

#define MFMA16(a, b, c) __builtin_amdgcn_mfma_f32_16x16x32_bf16((a), (b), (c), 0, 0, 0)

// fp32 -> bf16 bits, round-nearest-even
static __device__ __forceinline__ u16 f2b(float x) {
  unsigned u = __float_as_uint(x);
  u += 0x7fffu + ((u >> 16) & 1u);
  return (u16)(u >> 16);
}
static __device__ __forceinline__ float b2f(u16 b) {
  return __uint_as_float(((unsigned)b) << 16);
}

// async global->LDS, 16 B/lane (dest = wave-uniform base + lane*16)
static __device__ __forceinline__ void gload16(const void* g, void* l) {
  __builtin_amdgcn_global_load_lds(
      (const __attribute__((address_space(1))) u32*)g,
      (__attribute__((address_space(3))) u32*)l, 16, 0, 0);
}

// ---------------------------------------------------------------------------
// fp32 -> bf16, 3 tensors in one launch (z = which).  8 elems/thread.
// ---------------------------------------------------------------------------
__global__ __launch_bounds__(256) void conv3(
    const float* __restrict__ A0, const float* __restrict__ A1,
    const float* __restrict__ A2,
    u16* __restrict__ O0, u16* __restrict__ O1, u16* __restrict__ O2)
{
  const int z = blockIdx.y;
  const float* A = z == 0 ? A0 : (z == 1 ? A1 : A2);
  u16* O = z == 0 ? O0 : (z == 1 ? O1 : O2);
  const int i8 = (blockIdx.x * 256 + threadIdx.x) * 8;
  const float4 v0 = *(const float4*)&A[i8];
  const float4 v1 = *(const float4*)&A[i8 + 4];
  u16x8 o;
  o[0] = f2b(v0.x); o[1] = f2b(v0.y); o[2] = f2b(v0.z); o[3] = f2b(v0.w);
  o[4] = f2b(v1.x); o[5] = f2b(v1.y); o[6] = f2b(v1.z); o[7] = f2b(v1.w);
  *(u16x8*)&O[i8] = o;
}

// ---------------------------------------------------------------------------
// W fp32 [1024][1024] -> W2 [1024][2048] bf16 (hi | lo) — out-proj only.
// ---------------------------------------------------------------------------
__global__ __launch_bounds__(256) void conv_w_split(
    const float* __restrict__ W, u16* __restrict__ W2)
{
  const int i8 = (blockIdx.x * 256 + threadIdx.x) * 8;
  const int row = i8 >> 10, col = i8 & 1023;
  const float4 v0 = *(const float4*)&W[i8];
  const float4 v1 = *(const float4*)&W[i8 + 4];
  u16x8 h, l;
  h[0] = f2b(v0.x); l[0] = f2b(v0.x - b2f(h[0]));
  h[1] = f2b(v0.y); l[1] = f2b(v0.y - b2f(h[1]));
  h[2] = f2b(v0.z); l[2] = f2b(v0.z - b2f(h[2]));
  h[3] = f2b(v0.w); l[3] = f2b(v0.w - b2f(h[3]));
  h[4] = f2b(v1.x); l[4] = f2b(v1.x - b2f(h[4]));
  h[5] = f2b(v1.y); l[5] = f2b(v1.y - b2f(h[5]));
  h[6] = f2b(v1.z); l[6] = f2b(v1.z - b2f(h[6]));
  h[7] = f2b(v1.w); l[7] = f2b(v1.w - b2f(h[7]));
  u16* base = W2 + (size_t)row * 2048;
  *(u16x8*)&base[col]        = h;
  *(u16x8*)&base[1024 + col] = l;
}

// ---------------------------------------------------------------------------
// GEMM: C[m][n] = sum_k A[m][k]*W[n][k] + bias[n].  A bf16 [4096][1024].
// 128x128 tile, BK=32, 4 waves (2x2), per-wave 64x64 = 4x4 frags.
// Double-buffered global_load_lds, prefetch kt+1 while computing kt.
// omode 0: bf16 -> [B,H,S,64] (q/k)  1: bf16 -> [B,H,dk,S] (vT)  2: fp32
// ---------------------------------------------------------------------------
template<int NKT, int BSTRIDE>
__device__ __forceinline__ void gemm_body(
    const u16* __restrict__ A, const u16* __restrict__ B2,
    const float* __restrict__ bias, void* __restrict__ outp, const int omode)
{
  __shared__ __attribute__((aligned(16))) u16 As[2][128][32];
  __shared__ __attribute__((aligned(16))) u16 Bs[2][128][32];
  const int tid = threadIdx.x;
  const int m0 = blockIdx.x * 128, n0 = blockIdx.y * 128;
  const int w = tid >> 6, lane = tid & 63;
  const int wm = w >> 1, wn = w & 1;
  const int c = lane & 15, g = lane >> 4;

  const int sr = tid >> 2;            // staging row (i=0; i=1: +64)
  const int kc = (tid & 3) * 8;
  const u16* aP = A  + (size_t)(m0 + sr) * 1024 + kc;
  const u16* bP = B2 + (size_t)(n0 + sr) * BSTRIDE + kc;
  char* aD = (char*)As + w * 1024;
  char* bD = (char*)Bs + w * 1024;

  f32x4 acc[4][4];
  #pragma unroll
  for (int nf = 0; nf < 4; ++nf) {
    const float bv = bias[n0 + wn * 64 + nf * 16 + c];
    #pragma unroll
    for (int mf = 0; mf < 4; ++mf) acc[mf][nf] = (f32x4){bv, bv, bv, bv};
  }

  // prologue: stage kt=0 into buf 0
  gload16(aP,                        aD);
  gload16(aP + 64 * 1024,            aD + 4096);
  gload16(bP,                        bD);
  gload16(bP + (size_t)64 * BSTRIDE, bD + 4096);
  __syncthreads();

  for (int kt = 0; kt < NKT; ++kt) {
    const int cur = kt & 1;
    if (kt < NKT - 1) {
      const int kn = kt + 1;
      const u16* a  = aP + (kn & 31) * 32;
      const u16* bb = bP + kn * 32;
      char* ad = aD + (cur ^ 1) * 8192;
      char* bd = bD + (cur ^ 1) * 8192;
      gload16(a,                         ad);
      gload16(a + 64 * 1024,             ad + 4096);
      gload16(bb,                        bd);
      gload16(bb + (size_t)64 * BSTRIDE, bd + 4096);
    }
    const char* ab  = (const char*)As + cur * 8192;
    const char* bbk = (const char*)Bs + cur * 8192;
    s16x8 af[4], bf_[4];
    #pragma unroll
    for (int mf = 0; mf < 4; ++mf)
      af[mf] = *(const s16x8*)(ab + (wm * 64 + mf * 16 + c) * 64 + g * 16);
    #pragma unroll
    for (int nf = 0; nf < 4; ++nf)
      bf_[nf] = *(const s16x8*)(bbk + (wn * 64 + nf * 16 + c) * 64 + g * 16);
    #pragma unroll
    for (int mf = 0; mf < 4; ++mf)
      #pragma unroll
      for (int nf = 0; nf < 4; ++nf)
        acc[mf][nf] = MFMA16(af[mf], bf_[nf], acc[mf][nf]);
    __syncthreads();
  }

  // epilogue: m = m0+wm*64+mf*16+g*4+r ; n = n0+wn*64+nf*16+c
  #pragma unroll
  for (int mf = 0; mf < 4; ++mf) {
    #pragma unroll
    for (int nf = 0; nf < 4; ++nf) {
      const int mbase = m0 + wm * 64 + mf * 16 + g * 4;
      const int n = n0 + wn * 64 + nf * 16 + c;
      if (omode == 0) {
        u16* O = (u16*)outp;
        #pragma unroll
        for (int r = 0; r < 4; ++r) {
          const int m = mbase + r;
          const int b = m >> 10, sl = m & 1023, h = n >> 6, dk = n & 63;
          O[((size_t)(b * 16 + h) * 1024 + sl) * 64 + dk] = f2b(acc[mf][nf][r]);
        }
      } else if (omode == 1) {
        u16* O = (u16*)outp;
        ushort4 pk;
        pk.x = f2b(acc[mf][nf][0]);
        pk.y = f2b(acc[mf][nf][1]);
        pk.z = f2b(acc[mf][nf][2]);
        pk.w = f2b(acc[mf][nf][3]);
        const int b = mbase >> 10, sl = mbase & 1023, h = n >> 6, dk = n & 63;
        *(ushort4*)&O[((size_t)(b * 16 + h) * 64 + dk) * 1024 + sl] = pk;
      } else {
        float* O = (float*)outp;
        #pragma unroll
        for (int r = 0; r < 4; ++r)
          O[(size_t)(mbase + r) * 1024 + n] = acc[mf][nf][r];
      }
    }
  }
}

__global__ __launch_bounds__(256) void gemm_qkv(
    const u16* __restrict__ Xq, const u16* __restrict__ Xk, const u16* __restrict__ Xv,
    const u16* __restrict__ Wqb, const u16* __restrict__ Wkb, const u16* __restrict__ Wvb,
    const float* __restrict__ bq, const float* __restrict__ bk, const float* __restrict__ bv,
    u16* __restrict__ q2g, u16* __restrict__ k2g, u16* __restrict__ vTg)
{
  const int z = blockIdx.z;
  const u16* A    = z == 0 ? Xq  : (z == 1 ? Xk  : Xv);
  const u16* B2   = z == 0 ? Wqb : (z == 1 ? Wkb : Wvb);
  const float* bb = z == 0 ? bq  : (z == 1 ? bk  : bv);
  void* O         = z == 0 ? (void*)q2g : (z == 1 ? (void*)k2g : (void*)vTg);
  gemm_body<32, 1024>(A, B2, bb, O, z == 2 ? 1 : 0);
}

__global__ __launch_bounds__(256) void gemm_out2(
    const u16* __restrict__ A, const u16* __restrict__ B2,
    const float* __restrict__ bias, float* __restrict__ out)
{
  gemm_body<64, 2048>(A, B2, bias, out, 2);
}

// ---------------------------------------------------------------------------
// kmaxg[bh] = max over kv rows of ||k_row|| (bf16 values), * safety margin.
// ---------------------------------------------------------------------------
__global__ __launch_bounds__(256) void kmax_k(
    const u16* __restrict__ k2g, float* __restrict__ kmaxg)
{
  const int bh = blockIdx.x;
  const u16* base = k2g + (size_t)bh * (SEQ * DKH);
  const int tid = threadIdx.x;
  float mx = 0.f;
  #pragma unroll
  for (int rr = 0; rr < 4; ++rr) {
    const int row = rr * 256 + tid;
    float s = 0.f;
    #pragma unroll
    for (int j = 0; j < 8; ++j) {
      const u16x8 v = *(const u16x8*)&base[row * 64 + j * 8];
      #pragma unroll
      for (int q = 0; q < 8; ++q) { const float f = b2f(v[q]); s = fmaf(f, f, s); }
    }
    mx = fmaxf(mx, s);
  }
  #pragma unroll
  for (int off = 1; off < 64; off <<= 1) mx = fmaxf(mx, __shfl_xor(mx, off, 64));
  __shared__ float red[4];
  if ((tid & 63) == 0) red[tid >> 6] = mx;
  __syncthreads();
  if (tid == 0) {
    const float m = fmaxf(fmaxf(red[0], red[1]), fmaxf(red[2], red[3]));
    kmaxg[bh] = sqrtf(m) * 1.0005f;
  }
}

// ---------------------------------------------------------------------------
// MFMA flash attention, rel-pos bias, static-bound softmax (round-6 scheme),
// QB=128 (512 thr, 8 waves; per-wave code identical to round 6), and
// XCD-AWARE BLOCK MAPPING: flat grid 512; xcd = id&7, all 8 q-blocks of a
// head share one XCD -> per-XCD K/V working set 2 MB (L2-resident), staging
// becomes L2-hit and the 4x HBM over-fetch disappears.
// K/V tiles (64x64) staged via swizzled global_load_lds, double-buffered.
// LDS 70 KB -> 2 blocks/CU (16 waves/CU).
// ---------------------------------------------------------------------------
__global__ __launch_bounds__(512) void attn5(
    const u16* __restrict__ q2g, const u16* __restrict__ k2g,
    const u16* __restrict__ vTg, const float* __restrict__ rel,
    const float* __restrict__ kmaxg, u16* __restrict__ ctx)
{
  __shared__ __attribute__((aligned(16))) u16 up_s[128][76];  // q (pre) / p (loop)
  __shared__ __attribute__((aligned(16))) u16 k_s[2][4096];
  __shared__ __attribute__((aligned(16))) u16 v_s[2][4096];
  __shared__ float bias_s[128][33];
  __shared__ float bound_s[128];

  const int tid = threadIdx.x;
  const int w = tid >> 6, lane = tid & 63;      // 8 waves
  const int c = lane & 15, g = lane >> 4;
  // XCD-aware decode: id%8 selects XCD (HW round-robin); head pinned to XCD.
  const int flat = blockIdx.x;                  // 0..511
  const int xcd = flat & 7, slot = flat >> 3;
  const int qt = slot >> 3;                     // 0..7  (128-row q block)
  const int bh = (slot & 7) * 8 + xcd;          // 0..63
  const int b = bh >> 4, hd = bh & 15;
  const int l0 = qt * 128;
  u16* qs = &up_s[0][0];                        // flat [128*64] during preamble

  const u16* kbase = k2g + (size_t)bh * (SEQ * DKH);   // [S][64]
  const u16* vbase = vTg + (size_t)bh * (DKH * SEQ);   // [64][S]

  // staging: chunk D = tid -> (r=D>>3, jj=D&7); source chunk j = jj^(r&7);
  // LDS dest linear (wave w covers bytes w*1024..+1023).
  const int r0 = tid >> 3;
  const int j0 = (tid & 7) ^ (r0 & 7);
  const u16* kP = kbase + (size_t)r0 * 64 + j0 * 8;
  const u16* vP = vbase + (size_t)r0 * 1024 + j0 * 8;
  char* kD = (char*)k_s + w * 1024;
  char* vD = (char*)v_s + w * 1024;

  // ---- one-time q stage (128x64) + async stage of K/V tile 0 ----
  const u16* qsrc = q2g + ((size_t)bh * SEQ + l0) * 64;
  #pragma unroll
  for (int i = 0; i < 2; ++i) {
    const int f16 = tid * 2 + i;                // 0..1023 chunks
    const int r = f16 >> 3, ch = (f16 & 7) * 8;
    *(uint4*)&qs[r * 64 + ch] = *(const uint4*)&qsrc[r * 64 + ch];
  }
  gload16(kP, kD);
  gload16(vP, vD);
  __syncthreads();

  // ---- per-wave q fragments (before p overwrites the union) ----
  s16x8 qf[2];
  #pragma unroll
  for (int ks = 0; ks < 2; ++ks)
    qf[ks] = *(const s16x8*)&qs[(w * 16 + c) * 64 + ks * 32 + g * 8];

  // ---- bias table: bias_s[r][j] = q_r . rel[j] (rotated cols) ----
  const int rot = (tid & 31) * 2;
  for (int e = tid; e < 128 * NREL; e += 512) {
    const int r = e / NREL;
    const int j = e - r * NREL;
    float s = 0.f;
    for (int d0 = 0; d0 < 64; ++d0) {
      const int d = (d0 + rot) & 63;
      s = fmaf(b2f(qs[r * 64 + d]), rel[j * 64 + d], s);
    }
    bias_s[r][j] = s;
  }
  __syncthreads();

  // ---- per-row static bound (Cauchy-Schwarz + max bias) ----
  if (tid < 128) {
    float q2 = 0.f;
    for (int d0 = 0; d0 < 64; ++d0) {
      const int d = (d0 + rot) & 63;
      const float qv = b2f(qs[tid * 64 + d]);
      q2 = fmaf(qv, qv, q2);
    }
    float mb = bias_s[tid][0];
    #pragma unroll
    for (int j = 1; j < NREL; ++j) mb = fmaxf(mb, bias_s[tid][j]);
    bound_s[tid] = sqrtf(q2) * 1.0005f * kmaxg[bh] * 0.125f + mb;
  }
  __syncthreads();   // bound ready; q dead -> union becomes p

  const int qb = w * 16 + g * 4;
  float bnd[4], cr0[4], cr32[4], part[4];
  #pragma unroll
  for (int r = 0; r < 4; ++r) {
    const int rr = qb + r;
    bnd[r]  = bound_s[rr];
    cr0[r]  = bias_s[rr][0]  - bnd[r];
    cr32[r] = bias_s[rr][32] - bnd[r];
    part[r] = 0.f;
  }
  f32x4 oacc[4];
  #pragma unroll
  for (int fd = 0; fd < 4; ++fd) oacc[fd] = (f32x4){0.f, 0.f, 0.f, 0.f};

  // swizzled read chunk offsets (bytes) for ks = 0,1
  const int cj = c & 7;
  const int jx0 = ((0 + g) ^ cj) * 16;
  const int jx1 = ((4 + g) ^ cj) * 16;

  for (int kt = 0; kt < SEQ / 64; ++kt) {
    const int cur = kt & 1;
    if (kt < SEQ / 64 - 1) {             // prefetch tile kt+1
      gload16(kP + (size_t)(kt + 1) * 4096, kD + (cur ^ 1) * 8192);
      gload16(vP + (size_t)(kt + 1) * 64,   vD + (cur ^ 1) * 8192);
    }

    // ---- QK^T from swizzled K tile ----
    const char* kb = (const char*)k_s + cur * 8192;
    f32x4 sc[4];
    #pragma unroll
    for (int f = 0; f < 4; ++f) {
      const int rb = (f * 16 + c) * 128;
      const s16x8 kf0 = *(const s16x8*)(kb + rb + jx0);
      const s16x8 kf1 = *(const s16x8*)(kb + rb + jx1);
      sc[f] = (f32x4){0.f, 0.f, 0.f, 0.f};
      sc[f] = MFMA16(qf[0], kf0, sc[f]);
      sc[f] = MFMA16(qf[1], kf1, sc[f]);
    }

    // ---- static-bound softmax (no per-tile reductions) ----
    // uniform clipped distance iff kt <= 2qt-2 (low) or kt >= 2qt+3 (high)
    const bool diag = (kt >= 2 * qt - 1) && (kt <= 2 * qt + 2);
    if (!diag) {
      #pragma unroll
      for (int r = 0; r < 4; ++r) {
        const float cr = (kt < 2 * qt) ? cr0[r] : cr32[r];
        #pragma unroll
        for (int f = 0; f < 4; ++f) {
          const float sv = __expf(fmaf(sc[f][r], 0.125f, cr));
          part[r] += sv;
          up_s[qb + r][f * 16 + c] = f2b(sv);
        }
      }
    } else {
      #pragma unroll
      for (int r = 0; r < 4; ++r) {
        const int rowg = l0 + qb + r;
        #pragma unroll
        for (int f = 0; f < 4; ++f) {
          const int colg = kt * 64 + f * 16 + c;
          int dd = colg - rowg;
          dd = (dd < -16 ? -16 : (dd > 16 ? 16 : dd)) + 16;
          const float sv = __expf(fmaf(sc[f][r], 0.125f, bias_s[qb + r][dd] - bnd[r]));
          part[r] += sv;
          up_s[qb + r][f * 16 + c] = f2b(sv);
        }
      }
    }

    // ---- P.V: wave-private p rows + swizzled V tile ----
    const char* vb = (const char*)v_s + cur * 8192;
    #pragma unroll
    for (int ks = 0; ks < 2; ++ks) {
      const s16x8 pa = *(const s16x8*)&up_s[w * 16 + c][ks * 32 + g * 8];
      const int jx = ks ? jx1 : jx0;
      #pragma unroll
      for (int fd = 0; fd < 4; ++fd) {
        const s16x8 vv = *(const s16x8*)(vb + (fd * 16 + c) * 128 + jx);
        oacc[fd] = MFMA16(pa, vv, oacc[fd]);
      }
    }
    __syncthreads();   // drains prefetch + protects buffer/p reuse
  }

  // ---- one final c-lane reduction, normalize, write ----
  #pragma unroll
  for (int r = 0; r < 4; ++r) {
    #pragma unroll
    for (int off = 1; off < 16; off <<= 1) part[r] += __shfl_xor(part[r], off, 64);
  }
  #pragma unroll
  for (int r = 0; r < 4; ++r) {
    const float inv = 1.0f / part[r];
    const int row = l0 + qb + r;
    #pragma unroll
    for (int fd = 0; fd < 4; ++fd)
      ctx[((size_t)b * 1024 + row) * 1024 + hd * 64 + fd * 16 + c] = f2b(oacc[fd][r] * inv);
  }
}

// ---------------------------------------------------------------------------
extern "C" void kernel_launch(void* const* d_in, const int* in_sizes, int n_in,
                              void* d_out, int out_size, void* d_ws, size_t ws_size,
                              hipStream_t stream)
{
  (void)in_sizes; (void)n_in; (void)out_size; (void)ws_size;
  const float* Q   = (const float*)d_in[0];
  const float* K   = (const float*)d_in[1];
  const float* V   = (const float*)d_in[2];
  const float* Wq  = (const float*)d_in[3];
  const float* bq  = (const float*)d_in[4];
  const float* Wk  = (const float*)d_in[5];
  const float* bk  = (const float*)d_in[6];
  const float* Wv  = (const float*)d_in[7];
  const float* bv  = (const float*)d_in[8];
  const float* Wo  = (const float*)d_in[9];
  const float* bo  = (const float*)d_in[10];
  const float* rel = (const float*)d_in[11];
  float* out = (float*)d_out;

  // ws map (bytes), peak ~56.6 MB:
  //   Xq 0 | Xk 8.39M | Xv 16.78M | Wqb 25.17M (2M) | Wkb 27.26M | Wvb 29.36M
  //   | q2g 31.46M | k2g 39.85M | vTg 48.23M | kmaxg 56.62M
  // ctx reuses Xq, W2o reuses Xk — both dead after gemm_qkv.
  char* ws = (char*)d_ws;
  u16* Xq   = (u16*)(ws);
  u16* Xk   = (u16*)(ws + 8388608);
  u16* Xv   = (u16*)(ws + 16777216);
  u16* Wqb  = (u16*)(ws + 25165824);
  u16* Wkb  = (u16*)(ws + 27262976);
  u16* Wvb  = (u16*)(ws + 29360128);
  u16* q2g  = (u16*)(ws + 31457280);
  u16* k2g  = (u16*)(ws + 39845888);
  u16* vTg  = (u16*)(ws + 48234496);
  float* kmaxg = (float*)(ws + 56623104);
  u16* ctx  = Xq;
  u16* W2o  = Xk;

  const dim3 blk(256);
  conv3<<<dim3(2048, 3), blk, 0, stream>>>(Q, K, V, Xq, Xk, Xv);
  conv3<<<dim3(512, 3),  blk, 0, stream>>>(Wq, Wk, Wv, Wqb, Wkb, Wvb);

  gemm_qkv<<<dim3(32, 8, 3), blk, 0, stream>>>(Xq, Xk, Xv, Wqb, Wkb, Wvb,
                                               bq, bk, bv, q2g, k2g, vTg);

  kmax_k<<<dim3(NHEADS * BATCH), blk, 0, stream>>>(k2g, kmaxg);
  conv_w_split<<<dim3(512), blk, 0, stream>>>(Wo, W2o);

  attn5<<<dim3(512), dim3(512), 0, stream>>>(q2g, k2g, vTg, rel, kmaxg, ctx);

  gemm_out2<<<dim3(32, 8), blk, 0, stream>>>(ctx, W2o, bo, out);
}

// Round 8
// 263.035 us; speedup vs baseline: 1.5160x; 1.3653x over previous
//
#include <hip/hip_runtime.h>
#include <math.h>

#define DMODEL 1024
#define NHEADS 16
#define DKH    64
#define SEQ    1024
#define BATCH  4
#define NREL   33

typedef unsigned short u16;
typedef unsigned int   u32;
typedef short s16x8 __attribute__((ext_vector_type(8)));
typedef u16   u16x8 __attribute__((ext_vector_type(8)));
typedef float f32x4 __attribute__((ext_vector_type(4)));

#define MFMA16(a, b, c) __builtin_amdgcn_mfma_f32_16x16x32_bf16((a), (b), (c), 0, 0, 0)

// fp32 -> bf16 bits, round-nearest-even
static __device__ __forceinline__ u16 f2b(float x) {
  unsigned u = __float_as_uint(x);
  u += 0x7fffu + ((u >> 16) & 1u);
  return (u16)(u >> 16);
}
static __device__ __forceinline__ float b2f(u16 b) {
  return __uint_as_float(((unsigned)b) << 16);
}

// async global->LDS, 16 B/lane (dest = wave-uniform base + lane*16)
static __device__ __forceinline__ void gload16(const void* g, void* l) {
  __builtin_amdgcn_global_load_lds(
      (const __attribute__((address_space(1))) u32*)g,
      (__attribute__((address_space(3))) u32*)l, 16, 0, 0);
}

// ---------------------------------------------------------------------------
// fp32 -> bf16, 3 tensors in one launch (z = which).  8 elems/thread.
// ---------------------------------------------------------------------------
__global__ __launch_bounds__(256) void conv3(
    const float* __restrict__ A0, const float* __restrict__ A1,
    const float* __restrict__ A2,
    u16* __restrict__ O0, u16* __restrict__ O1, u16* __restrict__ O2)
{
  const int z = blockIdx.y;
  const float* A = z == 0 ? A0 : (z == 1 ? A1 : A2);
  u16* O = z == 0 ? O0 : (z == 1 ? O1 : O2);
  const int i8 = (blockIdx.x * 256 + threadIdx.x) * 8;
  const float4 v0 = *(const float4*)&A[i8];
  const float4 v1 = *(const float4*)&A[i8 + 4];
  u16x8 o;
  o[0] = f2b(v0.x); o[1] = f2b(v0.y); o[2] = f2b(v0.z); o[3] = f2b(v0.w);
  o[4] = f2b(v1.x); o[5] = f2b(v1.y); o[6] = f2b(v1.z); o[7] = f2b(v1.w);
  *(u16x8*)&O[i8] = o;
}

// ---------------------------------------------------------------------------
// W fp32 [1024][1024] -> W2 [1024][2048] bf16 (hi | lo) — out-proj only.
// ---------------------------------------------------------------------------
__global__ __launch_bounds__(256) void conv_w_split(
    const float* __restrict__ W, u16* __restrict__ W2)
{
  const int i8 = (blockIdx.x * 256 + threadIdx.x) * 8;
  const int row = i8 >> 10, col = i8 & 1023;
  const float4 v0 = *(const float4*)&W[i8];
  const float4 v1 = *(const float4*)&W[i8 + 4];
  u16x8 h, l;
  h[0] = f2b(v0.x); l[0] = f2b(v0.x - b2f(h[0]));
  h[1] = f2b(v0.y); l[1] = f2b(v0.y - b2f(h[1]));
  h[2] = f2b(v0.z); l[2] = f2b(v0.z - b2f(h[2]));
  h[3] = f2b(v0.w); l[3] = f2b(v0.w - b2f(h[3]));
  h[4] = f2b(v1.x); l[4] = f2b(v1.x - b2f(h[4]));
  h[5] = f2b(v1.y); l[5] = f2b(v1.y - b2f(h[5]));
  h[6] = f2b(v1.z); l[6] = f2b(v1.z - b2f(h[6]));
  h[7] = f2b(v1.w); l[7] = f2b(v1.w - b2f(h[7]));
  u16* base = W2 + (size_t)row * 2048;
  *(u16x8*)&base[col]        = h;
  *(u16x8*)&base[1024 + col] = l;
}

// ---------------------------------------------------------------------------
// GEMM: C[m][n] = sum_k A[m][k]*W[n][k] + bias[n].  A bf16 [4096][1024].
// 128x128 tile, BK=32, 4 waves (2x2), per-wave 64x64 = 4x4 frags.
// Double-buffered global_load_lds, prefetch kt+1 while computing kt.
// omode 0: bf16 -> [B,H,S,64] (q/k) — epilogue LDS-transpose, ushort8 stores
// omode 1: bf16 -> [B,H,dk,S] (vT)   omode 2: fp32 -> [4096][1024]
// ---------------------------------------------------------------------------
template<int NKT, int BSTRIDE>
__device__ __forceinline__ void gemm_body(
    const u16* __restrict__ A, const u16* __restrict__ B2,
    const float* __restrict__ bias, void* __restrict__ outp, const int omode)
{
  __shared__ __attribute__((aligned(16))) u16 As[2][128][32];
  __shared__ __attribute__((aligned(16))) u16 Bs[2][128][32];
  const int tid = threadIdx.x;
  const int m0 = blockIdx.x * 128, n0 = blockIdx.y * 128;
  const int w = tid >> 6, lane = tid & 63;
  const int wm = w >> 1, wn = w & 1;
  const int c = lane & 15, g = lane >> 4;

  const int sr = tid >> 2;            // staging row (i=0; i=1: +64)
  const int kc = (tid & 3) * 8;
  const u16* aP = A  + (size_t)(m0 + sr) * 1024 + kc;
  const u16* bP = B2 + (size_t)(n0 + sr) * BSTRIDE + kc;
  char* aD = (char*)As + w * 1024;
  char* bD = (char*)Bs + w * 1024;

  f32x4 acc[4][4];
  #pragma unroll
  for (int nf = 0; nf < 4; ++nf) {
    const float bv = bias[n0 + wn * 64 + nf * 16 + c];
    #pragma unroll
    for (int mf = 0; mf < 4; ++mf) acc[mf][nf] = (f32x4){bv, bv, bv, bv};
  }

  // prologue: stage kt=0 into buf 0
  gload16(aP,                        aD);
  gload16(aP + 64 * 1024,            aD + 4096);
  gload16(bP,                        bD);
  gload16(bP + (size_t)64 * BSTRIDE, bD + 4096);
  __syncthreads();

  for (int kt = 0; kt < NKT; ++kt) {
    const int cur = kt & 1;
    if (kt < NKT - 1) {
      const int kn = kt + 1;
      const u16* a  = aP + (kn & 31) * 32;
      const u16* bb = bP + kn * 32;
      char* ad = aD + (cur ^ 1) * 8192;
      char* bd = bD + (cur ^ 1) * 8192;
      gload16(a,                         ad);
      gload16(a + 64 * 1024,             ad + 4096);
      gload16(bb,                        bd);
      gload16(bb + (size_t)64 * BSTRIDE, bd + 4096);
    }
    const char* ab  = (const char*)As + cur * 8192;
    const char* bbk = (const char*)Bs + cur * 8192;
    s16x8 af[4], bf_[4];
    #pragma unroll
    for (int mf = 0; mf < 4; ++mf)
      af[mf] = *(const s16x8*)(ab + (wm * 64 + mf * 16 + c) * 64 + g * 16);
    #pragma unroll
    for (int nf = 0; nf < 4; ++nf)
      bf_[nf] = *(const s16x8*)(bbk + (wn * 64 + nf * 16 + c) * 64 + g * 16);
    #pragma unroll
    for (int mf = 0; mf < 4; ++mf)
      #pragma unroll
      for (int nf = 0; nf < 4; ++nf)
        acc[mf][nf] = MFMA16(af[mf], bf_[nf], acc[mf][nf]);
    __syncthreads();
  }

  // epilogue: m = m0+wm*64+mf*16+g*4+r ; n = n0+wn*64+nf*16+c
  if (omode == 0) {
    // LDS-transpose bounce: per-mf 32x128 u16 tile, coalesced ushort8 stores
    u16* O = (u16*)outp;
    u16* tile = (u16*)As;            // flat [32][136], 8.7 KB (As is dead)
    #pragma unroll
    for (int mf = 0; mf < 4; ++mf) {
      #pragma unroll
      for (int nf = 0; nf < 4; ++nf) {
        const int col = wn * 64 + nf * 16 + c;
        #pragma unroll
        for (int r = 0; r < 4; ++r)
          tile[(wm * 16 + g * 4 + r) * 136 + col] = f2b(acc[mf][nf][r]);
      }
      __syncthreads();
      #pragma unroll
      for (int t = 0; t < 2; ++t) {
        const int ch = tid * 2 + t;          // 512 chunks of 8 u16
        const int ri = ch >> 4, c8 = (ch & 15) * 8;
        const u16x8 vv = *(const u16x8*)&tile[ri * 136 + c8];
        const int m = m0 + (ri >> 4) * 64 + mf * 16 + (ri & 15);
        const int n = n0 + c8;
        const int b = m >> 10, sl = m & 1023, h = n >> 6, dk = n & 63;
        *(u16x8*)&O[((size_t)(b * 16 + h) * 1024 + sl) * 64 + dk] = vv;
      }
      __syncthreads();
    }
  } else {
    #pragma unroll
    for (int mf = 0; mf < 4; ++mf) {
      #pragma unroll
      for (int nf = 0; nf < 4; ++nf) {
        const int mbase = m0 + wm * 64 + mf * 16 + g * 4;
        const int n = n0 + wn * 64 + nf * 16 + c;
        if (omode == 1) {
          u16* O = (u16*)outp;
          ushort4 pk;
          pk.x = f2b(acc[mf][nf][0]);
          pk.y = f2b(acc[mf][nf][1]);
          pk.z = f2b(acc[mf][nf][2]);
          pk.w = f2b(acc[mf][nf][3]);
          const int b = mbase >> 10, sl = mbase & 1023, h = n >> 6, dk = n & 63;
          *(ushort4*)&O[((size_t)(b * 16 + h) * 64 + dk) * 1024 + sl] = pk;
        } else {
          float* O = (float*)outp;
          #pragma unroll
          for (int r = 0; r < 4; ++r)
            O[(size_t)(mbase + r) * 1024 + n] = acc[mf][nf][r];
        }
      }
    }
  }
}

__global__ __launch_bounds__(256) void gemm_qkv(
    const u16* __restrict__ Xq, const u16* __restrict__ Xk, const u16* __restrict__ Xv,
    const u16* __restrict__ Wqb, const u16* __restrict__ Wkb, const u16* __restrict__ Wvb,
    const float* __restrict__ bq, const float* __restrict__ bk, const float* __restrict__ bv,
    u16* __restrict__ q2g, u16* __restrict__ k2g, u16* __restrict__ vTg)
{
  const int z = blockIdx.z;
  const u16* A    = z == 0 ? Xq  : (z == 1 ? Xk  : Xv);
  const u16* B2   = z == 0 ? Wqb : (z == 1 ? Wkb : Wvb);
  const float* bb = z == 0 ? bq  : (z == 1 ? bk  : bv);
  void* O         = z == 0 ? (void*)q2g : (z == 1 ? (void*)k2g : (void*)vTg);
  gemm_body<32, 1024>(A, B2, bb, O, z == 2 ? 1 : 0);
}

__global__ __launch_bounds__(256) void gemm_out2(
    const u16* __restrict__ A, const u16* __restrict__ B2,
    const float* __restrict__ bias, float* __restrict__ out)
{
  gemm_body<64, 2048>(A, B2, bias, out, 2);
}

// ---------------------------------------------------------------------------
// kmaxg[bh] = max over kv rows of ||k_row|| (bf16 values), * safety margin.
// ---------------------------------------------------------------------------
__global__ __launch_bounds__(256) void kmax_k(
    const u16* __restrict__ k2g, float* __restrict__ kmaxg)
{
  const int bh = blockIdx.x;
  const u16* base = k2g + (size_t)bh * (SEQ * DKH);
  const int tid = threadIdx.x;
  float mx = 0.f;
  #pragma unroll
  for (int rr = 0; rr < 4; ++rr) {
    const int row = rr * 256 + tid;
    float s = 0.f;
    #pragma unroll
    for (int j = 0; j < 8; ++j) {
      const u16x8 v = *(const u16x8*)&base[row * 64 + j * 8];
      #pragma unroll
      for (int q = 0; q < 8; ++q) { const float f = b2f(v[q]); s = fmaf(f, f, s); }
    }
    mx = fmaxf(mx, s);
  }
  #pragma unroll
  for (int off = 1; off < 64; off <<= 1) mx = fmaxf(mx, __shfl_xor(mx, off, 64));
  __shared__ float red[4];
  if ((tid & 63) == 0) red[tid >> 6] = mx;
  __syncthreads();
  if (tid == 0) {
    const float m = fmaxf(fmaxf(red[0], red[1]), fmaxf(red[2], red[3]));
    kmaxg[bh] = sqrtf(m) * 1.0005f;
  }
}

// ---------------------------------------------------------------------------
// MFMA flash attention, rel-pos bias, static-bound softmax, XCD-aware block
// mapping (r7 scheme).  NEW: the bias table bias[r][j] = q_r . rel_j is now
// computed by MFMA (6 per wave, reusing the Q A-fragments) instead of 270k
// scalar ops + scattered rel loads — the r5-r7 ~40 us VALU preamble is gone.
// Row-max via in-register shfl; ||q||^2 via one vectorized LDS pass.
// All preamble producer/consumer pairs are intra-wave -> no extra barriers.
// ---------------------------------------------------------------------------
__global__ __launch_bounds__(512) void attn6(
    const u16* __restrict__ q2g, const u16* __restrict__ k2g,
    const u16* __restrict__ vTg, const float* __restrict__ rel,
    const float* __restrict__ kmaxg, u16* __restrict__ ctx)
{
  __shared__ __attribute__((aligned(16))) u16 up_s[128][76];  // q (pre) / p (loop)
  __shared__ __attribute__((aligned(16))) u16 k_s[2][4096];
  __shared__ __attribute__((aligned(16))) u16 v_s[2][4096];
  __shared__ float bias_s[128][33];
  __shared__ __attribute__((aligned(16))) u16 rel_s[48 * 64]; // bf16, rows>=33 zero
  __shared__ float q2_s[128];

  const int tid = threadIdx.x;
  const int w = tid >> 6, lane = tid & 63;      // 8 waves
  const int c = lane & 15, g = lane >> 4;
  const int flat = blockIdx.x;                  // 0..511
  const int xcd = flat & 7, slot = flat >> 3;
  const int qt = slot >> 3;                     // 0..7  (128-row q block)
  const int bh = (slot & 7) * 8 + xcd;          // 0..63
  const int b = bh >> 4, hd = bh & 15;
  const int l0 = qt * 128;
  u16* qs = &up_s[0][0];                        // flat [128*64] during preamble

  const u16* kbase = k2g + (size_t)bh * (SEQ * DKH);   // [S][64]
  const u16* vbase = vTg + (size_t)bh * (DKH * SEQ);   // [64][S]

  // K/V staging: chunk D = tid -> (r=D>>3, jj=D&7); source chunk j = jj^(r&7)
  const int r0 = tid >> 3;
  const int j0 = (tid & 7) ^ (r0 & 7);
  const u16* kP = kbase + (size_t)r0 * 64 + j0 * 8;
  const u16* vP = vbase + (size_t)r0 * 1024 + j0 * 8;
  char* kD = (char*)k_s + w * 1024;
  char* vD = (char*)v_s + w * 1024;

  // ---- one-time q stage (128x64) + rel->bf16 stage + K/V tile 0 ----
  const u16* qsrc = q2g + ((size_t)bh * SEQ + l0) * 64;
  #pragma unroll
  for (int i = 0; i < 2; ++i) {
    const int f16 = tid * 2 + i;
    const int r = f16 >> 3, ch = (f16 & 7) * 8;
    *(uint4*)&qs[r * 64 + ch] = *(const uint4*)&qsrc[r * 64 + ch];
  }
  if (tid < 384) {                               // 48 rows x 8 chunks
    const int rr = tid >> 3, c8 = (tid & 7) * 8;
    u16x8 o = (u16x8){0, 0, 0, 0, 0, 0, 0, 0};
    if (rr < NREL) {
      const float4 a0 = *(const float4*)&rel[rr * 64 + c8];
      const float4 a1 = *(const float4*)&rel[rr * 64 + c8 + 4];
      o[0] = f2b(a0.x); o[1] = f2b(a0.y); o[2] = f2b(a0.z); o[3] = f2b(a0.w);
      o[4] = f2b(a1.x); o[5] = f2b(a1.y); o[6] = f2b(a1.z); o[7] = f2b(a1.w);
    }
    *(u16x8*)&rel_s[rr * 64 + c8] = o;
  }
  gload16(kP, kD);
  gload16(vP, vD);
  __syncthreads();

  // ---- per-wave q fragments ----
  s16x8 qf[2];
  #pragma unroll
  for (int ks = 0; ks < 2; ++ks)
    qf[ks] = *(const s16x8*)&qs[(w * 16 + c) * 64 + ks * 32 + g * 8];

  // ---- bias table via MFMA: lane (c,g) reg r holds bias[qb+r][nf*16+c] ----
  const int qb = w * 16 + g * 4;
  f32x4 bac[3];
  #pragma unroll
  for (int nf = 0; nf < 3; ++nf) {
    f32x4 bb = (f32x4){0.f, 0.f, 0.f, 0.f};
    #pragma unroll
    for (int ks = 0; ks < 2; ++ks) {
      const s16x8 rf = *(const s16x8*)&rel_s[(nf * 16 + c) * 64 + ks * 32 + g * 8];
      bb = MFMA16(qf[ks], rf, bb);
    }
    bac[nf] = bb;
  }
  #pragma unroll
  for (int r = 0; r < 4; ++r) {
    bias_s[qb + r][c]      = bac[0][r];
    if (c == 0) bias_s[qb + r][32] = bac[2][r];
  }
  #pragma unroll
  for (int r = 0; r < 4; ++r)
    if (c + 16 < NREL) bias_s[qb + r][16 + c] = bac[1][r];

  // ---- per-row bias max (mask j>=33), reduced over the 16 c-lanes ----
  float mb[4];
  #pragma unroll
  for (int r = 0; r < 4; ++r) {
    float m = fmaxf(bac[0][r], bac[1][r]);
    m = fmaxf(m, (c == 0) ? bac[2][r] : -1e30f);
    mb[r] = m;
  }
  #pragma unroll
  for (int off = 1; off < 16; off <<= 1)
    #pragma unroll
    for (int r = 0; r < 4; ++r) mb[r] = fmaxf(mb[r], __shfl_xor(mb[r], off, 64));

  // ---- ||q_row||^2 (vectorized, conflict-free; intra-wave rows) ----
  {
    const int row = tid >> 2, qtr = tid & 3;
    float s = 0.f;
    #pragma unroll
    for (int t = 0; t < 2; ++t) {
      const u16x8 v = *(const u16x8*)&qs[row * 64 + qtr * 16 + t * 8];
      #pragma unroll
      for (int j = 0; j < 8; ++j) { const float f = b2f(v[j]); s = fmaf(f, f, s); }
    }
    s += __shfl_xor(s, 1, 64);
    s += __shfl_xor(s, 2, 64);
    if (qtr == 0) q2_s[row] = s;
  }

  // ---- per-row bound + off-diag constants (intra-wave ds ordering) ----
  const float km = kmaxg[bh] * 0.125f;
  float bnd[4], cr0[4], cr32[4], part[4];
  #pragma unroll
  for (int r = 0; r < 4; ++r) {
    bnd[r]  = sqrtf(q2_s[qb + r]) * 1.0005f * km + mb[r];
    cr0[r]  = bias_s[qb + r][0]  - bnd[r];
    cr32[r] = bias_s[qb + r][32] - bnd[r];
    part[r] = 0.f;
  }
  f32x4 oacc[4];
  #pragma unroll
  for (int fd = 0; fd < 4; ++fd) oacc[fd] = (f32x4){0.f, 0.f, 0.f, 0.f};
  __syncthreads();   // all q reads done -> union becomes p

  // swizzled read chunk offsets (bytes) for ks = 0,1
  const int cj = c & 7;
  const int jx0 = ((0 + g) ^ cj) * 16;
  const int jx1 = ((4 + g) ^ cj) * 16;

  for (int kt = 0; kt < SEQ / 64; ++kt) {
    const int cur = kt & 1;
    if (kt < SEQ / 64 - 1) {             // prefetch tile kt+1
      gload16(kP + (size_t)(kt + 1) * 4096, kD + (cur ^ 1) * 8192);
      gload16(vP + (size_t)(kt + 1) * 64,   vD + (cur ^ 1) * 8192);
    }

    // ---- QK^T from swizzled K tile ----
    const char* kb = (const char*)k_s + cur * 8192;
    f32x4 sc[4];
    #pragma unroll
    for (int f = 0; f < 4; ++f) {
      const int rb = (f * 16 + c) * 128;
      const s16x8 kf0 = *(const s16x8*)(kb + rb + jx0);
      const s16x8 kf1 = *(const s16x8*)(kb + rb + jx1);
      sc[f] = (f32x4){0.f, 0.f, 0.f, 0.f};
      sc[f] = MFMA16(qf[0], kf0, sc[f]);
      sc[f] = MFMA16(qf[1], kf1, sc[f]);
    }

    // ---- static-bound softmax (no per-tile reductions) ----
    const bool diag = (kt >= 2 * qt - 1) && (kt <= 2 * qt + 2);
    if (!diag) {
      #pragma unroll
      for (int r = 0; r < 4; ++r) {
        const float cr = (kt < 2 * qt) ? cr0[r] : cr32[r];
        #pragma unroll
        for (int f = 0; f < 4; ++f) {
          const float sv = __expf(fmaf(sc[f][r], 0.125f, cr));
          part[r] += sv;
          up_s[qb + r][f * 16 + c] = f2b(sv);
        }
      }
    } else {
      #pragma unroll
      for (int r = 0; r < 4; ++r) {
        const int rowg = l0 + qb + r;
        #pragma unroll
        for (int f = 0; f < 4; ++f) {
          const int colg = kt * 64 + f * 16 + c;
          int dd = colg - rowg;
          dd = (dd < -16 ? -16 : (dd > 16 ? 16 : dd)) + 16;
          const float sv = __expf(fmaf(sc[f][r], 0.125f, bias_s[qb + r][dd] - bnd[r]));
          part[r] += sv;
          up_s[qb + r][f * 16 + c] = f2b(sv);
        }
      }
    }

    // ---- P.V: wave-private p rows + swizzled V tile ----
    const char* vb = (const char*)v_s + cur * 8192;
    #pragma unroll
    for (int ks = 0; ks < 2; ++ks) {
      const s16x8 pa = *(const s16x8*)&up_s[w * 16 + c][ks * 32 + g * 8];
      const int jx = ks ? jx1 : jx0;
      #pragma unroll
      for (int fd = 0; fd < 4; ++fd) {
        const s16x8 vv = *(const s16x8*)(vb + (fd * 16 + c) * 128 + jx);
        oacc[fd] = MFMA16(pa, vv, oacc[fd]);
      }
    }
    __syncthreads();   // drains prefetch + protects buffer/p reuse
  }

  // ---- one final c-lane reduction, normalize, write ----
  #pragma unroll
  for (int r = 0; r < 4; ++r) {
    #pragma unroll
    for (int off = 1; off < 16; off <<= 1) part[r] += __shfl_xor(part[r], off, 64);
  }
  #pragma unroll
  for (int r = 0; r < 4; ++r) {
    const float inv = 1.0f / part[r];
    const int row = l0 + qb + r;
    #pragma unroll
    for (int fd = 0; fd < 4; ++fd)
      ctx[((size_t)b * 1024 + row) * 1024 + hd * 64 + fd * 16 + c] = f2b(oacc[fd][r] * inv);
  }
}

// ---------------------------------------------------------------------------
extern "C" void kernel_launch(void* const* d_in, const int* in_sizes, int n_in,
                              void* d_out, int out_size, void* d_ws, size_t ws_size,
                              hipStream_t stream)
{
  (void)in_sizes; (void)n_in; (void)out_size; (void)ws_size;
  const float* Q   = (const float*)d_in[0];
  const float* K   = (const float*)d_in[1];
  const float* V   = (const float*)d_in[2];
  const float* Wq  = (const float*)d_in[3];
  const float* bq  = (const float*)d_in[4];
  const float* Wk  = (const float*)d_in[5];
  const float* bk  = (const float*)d_in[6];
  const float* Wv  = (const float*)d_in[7];
  const float* bv  = (const float*)d_in[8];
  const float* Wo  = (const float*)d_in[9];
  const float* bo  = (const float*)d_in[10];
  const float* rel = (const float*)d_in[11];
  float* out = (float*)d_out;

  // ws map (bytes), peak ~56.6 MB:
  //   Xq 0 | Xk 8.39M | Xv 16.78M | Wqb 25.17M (2M) | Wkb 27.26M | Wvb 29.36M
  //   | q2g 31.46M | k2g 39.85M | vTg 48.23M | kmaxg 56.62M
  // ctx reuses Xq, W2o reuses Xk — both dead after gemm_qkv.
  char* ws = (char*)d_ws;
  u16* Xq   = (u16*)(ws);
  u16* Xk   = (u16*)(ws + 8388608);
  u16* Xv   = (u16*)(ws + 16777216);
  u16* Wqb  = (u16*)(ws + 25165824);
  u16* Wkb  = (u16*)(ws + 27262976);
  u16* Wvb  = (u16*)(ws + 29360128);
  u16* q2g  = (u16*)(ws + 31457280);
  u16* k2g  = (u16*)(ws + 39845888);
  u16* vTg  = (u16*)(ws + 48234496);
  float* kmaxg = (float*)(ws + 56623104);
  u16* ctx  = Xq;
  u16* W2o  = Xk;

  const dim3 blk(256);
  conv3<<<dim3(2048, 3), blk, 0, stream>>>(Q, K, V, Xq, Xk, Xv);
  conv3<<<dim3(512, 3),  blk, 0, stream>>>(Wq, Wk, Wv, Wqb, Wkb, Wvb);

  gemm_qkv<<<dim3(32, 8, 3), blk, 0, stream>>>(Xq, Xk, Xv, Wqb, Wkb, Wvb,
                                               bq, bk, bv, q2g, k2g, vTg);

  kmax_k<<<dim3(NHEADS * BATCH), blk, 0, stream>>>(k2g, kmaxg);
  conv_w_split<<<dim3(512), blk, 0, stream>>>(Wo, W2o);

  attn6<<<dim3(512), dim3(512), 0, stream>>>(q2g, k2g, vTg, rel, kmaxg, ctx);

  gemm_out2<<<dim3(32, 8), blk, 0, stream>>>(ctx, W2o, bo, out);
}